// Round 5
// baseline (296.299 us; speedup 1.0000x reference)
//
#include <hip/hip_runtime.h>
#include <cstdint>
#include <cstddef>

// ---------------------------------------------------------------------------
// DetCenterDense: fused conv3x3(128->64)+ReLU -> 4x conv1x1 heads (20 ch total,
// sigmoid on last 4) over [4,128,512,512] fp32, NCHW. bf16 MFMA implicit GEMM.
// R5: wave tile 128px x 64och (mt=4) -> reads/MFMA 0.75, block 4 rows x 128
//     cols, halo 1.5x. A: double-buffered LDS + 1-deep reg prefetch. B: single
//     LDS buffer via global_load_lds post-phase; simple vmcnt(0) drain (only B
//     outstanding there). 2 barriers/iter, 8 iters of 16 cin.
// ---------------------------------------------------------------------------

typedef __bf16 bf16x8 __attribute__((ext_vector_type(8)));
typedef __bf16 bf16x4 __attribute__((ext_vector_type(4)));
typedef float f32x16 __attribute__((ext_vector_type(16)));
typedef float f32x4v __attribute__((ext_vector_type(4)));
typedef float f32x2v __attribute__((ext_vector_type(2)));

// A-tile LDS swizzle (validated R3/R4): granule 16B at (slot s, octet o):
//   lin = s*32 + o*16 ; byte = lin ^ ((lin>>1)&0x10) ^ ((lin>>2)&0x60)
__device__ __forceinline__ int swz(int s, int o) {
    int lin = (s << 5) | (o << 4);
    return lin ^ ((lin >> 1) & 0x10) ^ ((lin >> 2) & 0x60);
}

// ---------------------------------------------------------------------------
// Prepass: repack w_shared [64][128][3][3] fp32 -> bf16, per-half-chunk
// contiguous: ws3 [hc(8)][tap(9)][hw(2)][och(64)][8 bf16]  (18432 B per hc)
// ---------------------------------------------------------------------------
__global__ void prep_w_kernel(const float* __restrict__ w, __bf16* __restrict__ ws3) {
    int idx = blockIdx.x * 256 + threadIdx.x;
    if (idx >= 64 * 128 * 9) return;
    int tap = idx % 9;
    int cin = (idx / 9) % 128;
    int och = idx / (9 * 128);
    int hc = cin >> 4;
    int hw = (cin >> 3) & 1;
    int j  = cin & 7;
    int dst = (((hc * 9 + tap) * 2 + hw) * 64 + och) * 8 + j;
    ws3[dst] = (__bf16)w[idx];
}

// LDS map (bytes):
//   A0 @ 0 [25344]  A1 @ 25344 [25344]   ([6 rows][132 slots][16 cin] bf16, swz)
//   B  @ 50688 [18432]  (single buf: [tap 9][hw 2][och 64][8 bf16], linear)
//   wc @ 69120 [4096]   bias @ 73216 [128]     total 73344 -> 2 blocks/CU
#define A_OFF(p)  ((p) ? 25344 : 0)
#define B_BASE    50688
#define WC_BASE   69120
#define BIAS_BASE 73216

__global__ __launch_bounds__(256, 2)
void det_main_kernel(const float* __restrict__ feature,
                     const __bf16* __restrict__ ws3,
                     const float* __restrict__ w_cls, const float* __restrict__ b_cls,
                     const float* __restrict__ w_box, const float* __restrict__ b_box,
                     const float* __restrict__ w_dir, const float* __restrict__ b_dir,
                     const float* __restrict__ w_scr, const float* __restrict__ b_scr,
                     float* __restrict__ out) {
    __shared__ __align__(1024) char s_all[73344];

    const int tid  = threadIdx.x;
    const int lane = tid & 63;
    const int wave = tid >> 6;
    const int l31  = lane & 31;
    const int hw   = lane >> 5;
    const int wcb  = wave * 32;     // wave's 32-col strip

    // XCD-aware decode: 2048 blocks -> 8 chunks of 256.
    const int bid = blockIdx.x;
    const int wg  = (bid & 7) * 256 + (bid >> 3);
    const int ck  = wg >> 8;            // 0..7
    const int bz  = ck >> 1;
    const int rem = wg & 255;
    const int h0  = (rem >> 1) * 4;
    const int w0  = ((ck & 1) * 2 + (rem & 1)) * 128;
    const size_t CH = 512 * 512;

    // ---- staging roles ----
    // full task (rows 0..3): [1 row][4 cols][8 cin] -> 8 dwordx4, 4 b128 writes
    const int t_r0 = tid >> 6;
    const int t_q  = (tid >> 1) & 31;
    const int t_o  = tid & 1;
    const int m_h  = h0 - 1 + t_r0;
    const bool m_ok = (m_h >= 0);                 // upper bound always fine
    const float* m_base = feature + (size_t)(bz * 128 + t_o * 8) * CH
                        + (size_t)(m_ok ? m_h : 0) * 512 + (w0 + 4 * t_q);
    // half task (rows 4,5): [1 row][4 cols][4 cin] -> 4 dwordx4, 4 b64 writes
    const int t_r1 = 4 + (tid >> 7);
    const int rem1 = tid & 127;
    const int t_hq = rem1 >> 2;
    const int t_ho = (rem1 >> 1) & 1;
    const int t_hh = rem1 & 1;
    const int hh_h = h0 - 1 + t_r1;
    const bool h_ok = (hh_h < 512);
    const float* h_base = feature + (size_t)(bz * 128 + t_ho * 8 + t_hh * 4) * CH
                        + (size_t)(h_ok ? hh_h : 0) * 512 + (w0 + 4 * t_hq);
    // edge cols (s=0: w0-1, s=129: w0+128): tid<192, 1 f32x2 each
    const bool e_on  = tid < 192;
    const int e_side = tid / 96;
    const int e_rem  = tid % 96;
    const int e_r    = e_rem >> 4;                 // 0..5
    const int e_c    = e_rem & 15;                 // cin
    const int e_h    = h0 - 1 + e_r;
    const int e_col  = e_side ? (w0 + 128) : (w0 - 2);
    const bool e_ok  = e_on && ((unsigned)e_h < 512u)
                     && (e_side ? (w0 + 128 < 512) : (w0 > 0));
    const float* e_base = feature + (size_t)(bz * 128 + e_c) * CH
                        + (size_t)(e_ok ? e_h : 0) * 512 + (e_ok ? e_col : 0);

    // ---- stage 1x1-head weights (bf16, row-swizzled) + bias into LDS ----
    {
        char* s_wc = s_all + WC_BASE;
        float* s_bias = (float*)(s_all + BIAS_BASE);
        int och = tid >> 3;
        int j8  = (tid & 7) * 8;
        float v[8];
        if (och < 20) {
            const float* src = (och < 2)  ? (w_cls + och * 64)
                             : (och < 8)  ? (w_box + (och - 2) * 64)
                             : (och < 16) ? (w_dir + (och - 8) * 64)
                                          : (w_scr + (och - 16) * 64);
            #pragma unroll
            for (int j = 0; j < 8; ++j) v[j] = src[j8 + j];
        } else {
            #pragma unroll
            for (int j = 0; j < 8; ++j) v[j] = 0.f;
        }
        bf16x8 wv;
        #pragma unroll
        for (int j = 0; j < 8; ++j) wv[j] = (__bf16)v[j];
        *(bf16x8*)(s_wc + och * 128 + ((j8 * 2) ^ ((och & 7) << 4))) = wv;
        if (tid < 32) {
            s_bias[tid] = (tid < 2)  ? b_cls[tid]
                        : (tid < 8)  ? b_box[tid - 2]
                        : (tid < 16) ? b_dir[tid - 8]
                        : (tid < 20) ? b_scr[tid - 16] : 0.f;
        }
    }

    f32x4v Rm[8];
    f32x4v Rh[4];
    f32x2v Re;

    auto issueA = [&](int hc) {
        const float* p = m_base + (size_t)(hc * 16) * CH;
        #pragma unroll
        for (int j = 0; j < 8; ++j) Rm[j] = *(const f32x4v*)(p + (size_t)j * CH);
        const float* p2 = h_base + (size_t)(hc * 16) * CH;
        #pragma unroll
        for (int j = 0; j < 4; ++j) Rh[j] = *(const f32x4v*)(p2 + (size_t)j * CH);
        if (e_on) Re = *(const f32x2v*)(e_base + (size_t)(hc * 16) * CH);
    };

    auto writeA = [&](int hc) {
        char* ab = s_all + A_OFF(hc & 1);
        #pragma unroll
        for (int k = 0; k < 4; ++k) {
            bf16x8 g;
            #pragma unroll
            for (int j = 0; j < 8; ++j) g[j] = (__bf16)(m_ok ? Rm[j][k] : 0.f);
            *(bf16x8*)(ab + t_r0 * 4224 + swz(4 * t_q + 1 + k, t_o)) = g;
        }
        #pragma unroll
        for (int k = 0; k < 4; ++k) {
            bf16x4 g;
            #pragma unroll
            for (int j = 0; j < 4; ++j) g[j] = (__bf16)(h_ok ? Rh[j][k] : 0.f);
            *(bf16x4*)(ab + t_r1 * 4224 + swz(4 * t_hq + 1 + k, t_ho) + t_hh * 8) = g;
        }
        if (e_on) {
            float v = e_side ? Re[0] : Re[1];
            *(__bf16*)(ab + e_r * 4224 + swz(e_side ? 129 : 0, e_c >> 3) + (e_c & 7) * 2)
                = (__bf16)(e_ok ? v : 0.f);
        }
    };

    auto issueB = [&](int hc) {
        char* bb = s_all + B_BASE;
        const char* src = (const char*)ws3 + hc * 18432;
        #pragma unroll
        for (int i = 0; i < 4; ++i) {
            int g0 = i * 256 + wave * 64;
            __builtin_amdgcn_global_load_lds(
                (const __attribute__((address_space(1))) void*)(src + (size_t)(g0 + lane) * 16),
                (__attribute__((address_space(3))) void*)(bb + g0 * 16), 16, 0, 0);
        }
        if (wave < 2) {
            int g0 = 1024 + wave * 64;
            __builtin_amdgcn_global_load_lds(
                (const __attribute__((address_space(1))) void*)(src + (size_t)(g0 + lane) * 16),
                (__attribute__((address_space(3))) void*)(bb + g0 * 16), 16, 0, 0);
        }
    };

    f32x16 zero16;
    #pragma unroll
    for (int e = 0; e < 16; ++e) zero16[e] = 0.f;
    f32x16 acc[4][2];
    #pragma unroll
    for (int mt = 0; mt < 4; ++mt) { acc[mt][0] = zero16; acc[mt][1] = zero16; }

    auto mfma_phase = [&](int hc) {
        const char* ab = s_all + A_OFF(hc & 1);
        const char* bb = s_all + B_BASE;
        #pragma unroll
        for (int tap = 0; tap < 9; ++tap) {
            const int kh = tap / 3, kw = tap % 3;
            bf16x8 Bf[2];
            #pragma unroll
            for (int nt = 0; nt < 2; ++nt)
                Bf[nt] = *(const bf16x8*)(bb + (size_t)((tap * 2 + hw) * 64 + nt * 32 + l31) * 16);
            bf16x8 Af[4];
            #pragma unroll
            for (int mt = 0; mt < 4; ++mt)
                Af[mt] = *(const bf16x8*)(ab + (mt + kh) * 4224 + swz(wcb + l31 + kw, hw));
            __builtin_amdgcn_s_setprio(1);
            #pragma unroll
            for (int mt = 0; mt < 4; ++mt) {
                acc[mt][0] = __builtin_amdgcn_mfma_f32_32x32x16_bf16(Af[mt], Bf[0], acc[mt][0], 0, 0, 0);
                acc[mt][1] = __builtin_amdgcn_mfma_f32_32x32x16_bf16(Af[mt], Bf[1], acc[mt][1], 0, 0, 0);
            }
            __builtin_amdgcn_s_setprio(0);
        }
    };

    // ---- prologue: B(0), A(0) staged; A(1) in flight across first barrier ----
    issueB(0);
    issueA(0);
    writeA(0);   // reg-deps drain A(0); B(0) older -> retired too
    issueA(1);
    __builtin_amdgcn_sched_barrier(0);
    asm volatile("s_waitcnt lgkmcnt(0)" ::: "memory");
    __builtin_amdgcn_s_barrier();
    __builtin_amdgcn_sched_barrier(0);

    // ---- main loop: 8 half-chunks of 16 cin, 2 barriers each ----
    #pragma unroll 1
    for (int h = 0; h < 8; ++h) {
        mfma_phase(h);
        __builtin_amdgcn_sched_barrier(0);
        __builtin_amdgcn_s_barrier();           // all waves done reading B(h)
        __builtin_amdgcn_sched_barrier(0);
        if (h == 7) break;
        issueB(h + 1);                          // overwrite B buffer (safe now)
        writeA(h + 1);                          // into A-buf[(h+1)&1]
        asm volatile("s_waitcnt vmcnt(0) lgkmcnt(0)" ::: "memory");  // only B outstanding here
        if (h < 6) issueA(h + 2);               // stays in flight across barrier
        __builtin_amdgcn_sched_barrier(0);
        __builtin_amdgcn_s_barrier();
        __builtin_amdgcn_sched_barrier(0);
    }

    // ---- ReLU -> bf16 X tile in LDS (reuse A region), row-XOR swizzled ----
    __bf16* X = (__bf16*)s_all;     // [512 px][64 ch] = 64 KB
    #pragma unroll
    for (int mt = 0; mt < 4; ++mt) {
        #pragma unroll
        for (int nt = 0; nt < 2; ++nt) {
            #pragma unroll
            for (int r = 0; r < 16; ++r) {
                float v = fmaxf(acc[mt][nt][r], 0.f);
                int mrow = (r & 3) + 8 * (r >> 2) + 4 * hw;
                int px   = mt * 128 + wcb + mrow;
                int ch   = nt * 32 + l31;
                int off  = px * 128 + ((ch * 2) ^ ((px & 7) << 4));
                *(__bf16*)((char*)X + off) = (__bf16)v;
            }
        }
    }
    // wave-local write->read: lgkmcnt ordering suffices

    // ---- stage 2: out[och(20->32)][128 px per wave] = Wc @ X, K=64 ----
    const char* s_wc = s_all + WC_BASE;
    const float* s_bias = (const float*)(s_all + BIAS_BASE);
    f32x16 acc2[4];
    #pragma unroll
    for (int pt = 0; pt < 4; ++pt) acc2[pt] = zero16;
    #pragma unroll
    for (int ks = 0; ks < 4; ++ks) {
        int ch0 = ks * 16 + hw * 8;
        bf16x8 a2 = *(const bf16x8*)(s_wc + l31 * 128 + ((ch0 * 2) ^ ((l31 & 7) << 4)));
        #pragma unroll
        for (int pt = 0; pt < 4; ++pt) {
            int px = pt * 128 + wcb + l31;
            int offB = px * 128 + ((ch0 * 2) ^ ((px & 7) << 4));
            bf16x8 b2 = *(const bf16x8*)((const char*)X + offB);
            acc2[pt] = __builtin_amdgcn_mfma_f32_32x32x16_bf16(a2, b2, acc2[pt], 0, 0, 0);
        }
    }

    // ---- epilogue: bias, sigmoid on och 16..19, coalesced stores ----
    #pragma unroll
    for (int pt = 0; pt < 4; ++pt) {
        int hrow = h0 + pt;
        int wcol = w0 + wcb + l31;
        #pragma unroll
        for (int r = 0; r < 16; ++r) {
            int och = (r & 3) + 8 * (r >> 2) + 4 * hw;
            if (och < 20) {
                float v = acc2[pt][r] + s_bias[och];
                if (och >= 16) v = 1.f / (1.f + __expf(-v));
                out[(((size_t)bz * 20 + och) * 512 + hrow) * 512 + wcol] = v;
            }
        }
    }
}

extern "C" void kernel_launch(void* const* d_in, const int* in_sizes, int n_in,
                              void* d_out, int out_size, void* d_ws, size_t ws_size,
                              hipStream_t stream) {
    const float* feature  = (const float*)d_in[0];
    const float* w_shared = (const float*)d_in[1];
    const float* w_cls = (const float*)d_in[2];
    const float* b_cls = (const float*)d_in[3];
    const float* w_box = (const float*)d_in[4];
    const float* b_box = (const float*)d_in[5];
    const float* w_dir = (const float*)d_in[6];
    const float* b_dir = (const float*)d_in[7];
    const float* w_scr = (const float*)d_in[8];
    const float* b_scr = (const float*)d_in[9];
    float* out = (float*)d_out;
    __bf16* ws3 = (__bf16*)d_ws;   // 8 * 18432 B = 147456 B

    prep_w_kernel<<<288, 256, 0, stream>>>(w_shared, ws3);

    det_main_kernel<<<2048, 256, 0, stream>>>(feature, ws3,
                                              w_cls, b_cls, w_box, b_box,
                                              w_dir, b_dir, w_scr, b_scr, out);
}